// Round 19
// baseline (169.987 us; speedup 1.0000x reference)
//
#include <hip/hip_runtime.h>

#define EPS_BN 1e-5f
typedef float v2f __attribute__((ext_vector_type(2)));

// ---------------- prep/compose + three_nn merged (r11-verified) ----------
struct LayerDesc {
    const float* W; const float* b; const float* bn;
    float* wt; float* shb; int O; int C;
};
struct HeadArgs {
    LayerDesc l[6];
    const float* a2w; const float* a2b; const float* w3; const float* b3; const float* bn3;
    float* w3c; float* sh3;
    const float* a1w; const float* a1b; const float* w5; const float* b5; const float* bn5;
    float* w5c; float* sh5;
    const float* xyz0; const float* xyz1; const float* xyz2;
    int* idx1; float* wgt1; int* idx2; float* wgt2;
};

__global__ __launch_bounds__(256) void head_kernel(HeadArgs a) {
    const int bx = blockIdx.x, tid = threadIdx.x;
    if (bx < 96) {
        LayerDesc d = a.l[bx / 16];
        int sub = bx % 16;
        int total = d.O * d.C;
        for (int i = sub * 256 + tid; i < total; i += 16 * 256) {
            int c = i / d.O, o = i - (i / d.O) * d.O;
            float sc = 1.f;
            if (d.bn) { float g = d.bn[o], v = d.bn[3 * d.O + o]; sc = g * rsqrtf(v + EPS_BN); }
            d.wt[i] = d.W[(size_t)o * d.C + c] * sc;
        }
        for (int o = sub * 256 + tid; o < d.O; o += 16 * 256) {
            float sc = 1.f, sh = 0.f;
            if (d.bn) {
                float g = d.bn[o], be = d.bn[d.O + o], m = d.bn[2 * d.O + o], v = d.bn[3 * d.O + o];
                sc = g * rsqrtf(v + EPS_BN); sh = be - m * sc;
            }
            d.shb[o] = d.b[o] * sc + sh;
        }
        return;
    } else if (bx < 169) {
        int e = (bx - 96) * 256 + tid;
        if (e < 128 * 144) {
            int k = e / 144, o = e - (e / 144) * 144;
            float sc = a.bn3[o] * rsqrtf(a.bn3[3 * 144 + o] + EPS_BN);
            float s = 0.f;
            for (int c = 0; c < 144; ++c)
                s += a.a2w[c * 128 + k] * a.w3[(size_t)o * 288 + 144 + c];
            a.w3c[k * 144 + o] = s * sc;
        } else if (e < 128 * 144 + 144) {
            int o = e - 128 * 144;
            float g = a.bn3[o], be = a.bn3[144 + o], m = a.bn3[2 * 144 + o], v = a.bn3[3 * 144 + o];
            float sc = g * rsqrtf(v + EPS_BN);
            float s = 0.f;
            for (int c = 0; c < 144; ++c) s += a.w3[(size_t)o * 288 + 144 + c] * a.a2b[c];
            a.sh3[o] = (s + a.b3[o] - m) * sc + be;
        }
        return;
    } else if (bx < 171) {
        int e = (bx - 169) * 256 + tid;
        if (e < 3 * 72) {
            int k = e / 72, o = e - (e / 72) * 72;
            float sc = a.bn5[o] * rsqrtf(a.bn5[3 * 72 + o] + EPS_BN);
            float s = 0.f;
            for (int c = 0; c < 72; ++c)
                s += a.a1w[c * 3 + k] * a.w5[(size_t)o * 144 + 72 + c];
            a.w5c[k * 72 + o] = s * sc;
        } else if (e < 3 * 72 + 72) {
            int o = e - 3 * 72;
            float g = a.bn5[o], be = a.bn5[72 + o], m = a.bn5[2 * 72 + o], v = a.bn5[3 * 72 + o];
            float sc = g * rsqrtf(v + EPS_BN);
            float s = 0.f;
            for (int c = 0; c < 72; ++c) s += a.w5[(size_t)o * 144 + 72 + c] * a.a1b[c];
            a.sh5[o] = (s + a.b5[o] - m) * sc + be;
        }
        return;
    }
    // ---- three_nn: 256 threads = 32 unknowns x 8 segments ----
    const int NSEG = 8;
    __shared__ float kl[3 * 1024];
    __shared__ float sd[NSEG][32][3];
    __shared__ int   si[NSEG][32][3];
    const float* unknown; const float* known;
    int Nu, Nk, blk, b; int* idx; float* wgt;
    int t = bx - 171;
    if (t < 64) {
        unknown = a.xyz1; known = a.xyz2; Nu = 1024; Nk = 256;
        b = t >> 5; blk = t & 31; idx = a.idx1; wgt = a.wgt1;
    } else {
        t -= 64;
        unknown = a.xyz0; known = a.xyz1; Nu = 4096; Nk = 1024;
        b = t >> 7; blk = t & 127; idx = a.idx2; wgt = a.wgt2;
    }
    for (int i = tid; i < Nk * 3; i += 256) kl[i] = known[(size_t)b * Nk * 3 + i];
    __syncthreads();
    const int u   = tid & 31;
    const int seg = tid >> 5;
    const int n   = blk * 32 + u;
    const float* up = unknown + ((size_t)b * Nu + n) * 3;
    const float ux = up[0], uy = up[1], uz = up[2];
    float d0 = 1e30f, d1 = 1e30f, d2 = 1e30f;
    int i0 = 0, i1 = 0, i2 = 0;
    const int klo = seg * (Nk / NSEG), khi = klo + Nk / NSEG;
    for (int k = klo; k < khi; ++k) {
        float dx = __fsub_rn(ux, kl[3 * k + 0]);
        float dy = __fsub_rn(uy, kl[3 * k + 1]);
        float dz = __fsub_rn(uz, kl[3 * k + 2]);
        float d = __fadd_rn(__fadd_rn(__fmul_rn(dx, dx), __fmul_rn(dy, dy)), __fmul_rn(dz, dz));
        if (d < d0)      { d2 = d1; i2 = i1; d1 = d0; i1 = i0; d0 = d; i0 = k; }
        else if (d < d1) { d2 = d1; i2 = i1; d1 = d;  i1 = k; }
        else if (d < d2) { d2 = d;  i2 = k; }
    }
    sd[seg][u][0] = d0; sd[seg][u][1] = d1; sd[seg][u][2] = d2;
    si[seg][u][0] = i0; si[seg][u][1] = i1; si[seg][u][2] = i2;
    __syncthreads();
    if (tid < 32) {
        float m0 = 1e30f, m1 = 1e30f, m2 = 1e30f;
        int j0 = 0, j1 = 0, j2 = 0;
        for (int s = 0; s < NSEG; ++s)
            for (int c = 0; c < 3; ++c) {
                float d = sd[s][u][c];
                int ii = si[s][u][c];
                if (d < m0)      { m2 = m1; j2 = j1; m1 = m0; j1 = j0; m0 = d; j0 = ii; }
                else if (d < m1) { m2 = m1; j2 = j1; m1 = d;  j1 = ii; }
                else if (d < m2) { m2 = d;  j2 = ii; }
            }
        float w0 = 1.f / (m0 + 1e-8f), w1 = 1.f / (m1 + 1e-8f), w2 = 1.f / (m2 + 1e-8f);
        float s = w0 + w1 + w2;
        size_t base = ((size_t)b * Nu + n) * 3;
        idx[base + 0] = j0; idx[base + 1] = j1; idx[base + 2] = j2;
        wgt[base + 0] = w0 / s; wgt[base + 1] = w1 / s; wgt[base + 2] = w2 / s;
    }
}

// ---------------- pipelined K-loop for one wave, OT=4 ----------------------
template <int CTW>
__device__ __forceinline__ void conv_kloop(
    const float* __restrict__ s0, int N, const float* wldsw, v2f (&acc)[4][2])
{
    static_assert(CTW % 8 == 0 || CTW % 8 == 4, "CT tail");
    auto loadrow = [&](float (&x)[4], int c) {
        float4 t = *reinterpret_cast<const float4*>(s0 + (size_t)c * N);
        x[0] = t.x; x[1] = t.y; x[2] = t.z; x[3] = t.w;
    };
    auto comprow = [&](const float (&x)[4], int c) {
        v2f x01; x01[0] = x[0]; x01[1] = x[1];
        v2f x23; x23[0] = x[2]; x23[1] = x[3];
        float4 wv = *reinterpret_cast<const float4*>(wldsw + c * 4);
        float ww[4] = {wv.x, wv.y, wv.z, wv.w};
#pragma unroll
        for (int r = 0; r < 4; ++r) {
            v2f w2; w2[0] = ww[r]; w2[1] = ww[r];
            acc[r][0] = __builtin_elementwise_fma(w2, x01, acc[r][0]);
            acc[r][1] = __builtin_elementwise_fma(w2, x23, acc[r][1]);
        }
    };
    auto loadg = [&](float (&buf)[4][4], int c) {
#pragma unroll
        for (int q = 0; q < 4; ++q) loadrow(buf[q], c + q);
    };
    auto compg = [&](const float (&buf)[4][4], int c) {
#pragma unroll
        for (int q = 0; q < 4; ++q) comprow(buf[q], c + q);
    };
    float xa[4][4], xb[4][4];
    loadg(xa, 0); loadg(xb, 4);
    int c = 0;
#pragma unroll 1
    for (; c + 16 <= CTW; c += 8) {
        compg(xa, c);     loadg(xa, c + 8);
        compg(xb, c + 4); loadg(xb, c + 12);
    }
    compg(xa, c);
    if constexpr (CTW % 8 == 4) {
        loadg(xa, c + 8);
        compg(xb, c + 4);
        compg(xa, c + 8);
    } else {
        compg(xb, c + 4);
    }
}

// ---------------- 4-wave K-split conv body (256 threads/block) -------------
template <int CA, int CB, int CC, int CD, int O, bool RELU, int ADD, bool TOUT>
__device__ __forceinline__ void conv4w(
    int nt, int ot, int nb, int tid,
    const float* __restrict__ src0, int qdiv0,
    const float* __restrict__ Wt, const float* __restrict__ shb,
    const float* __restrict__ basep, int qdivb,
    float* __restrict__ outp, int N, float* wlds, float* sred)
{
    constexpr int CT = CA + CB + CC + CD;
    const int wid = tid >> 6, lane = tid & 63;
    const int oBase = ot * 4;
    const int n0 = (nt * 64 + lane) * 4;

    for (int i = tid; i < CT * 4; i += 256)
        wlds[i] = Wt[(size_t)(i >> 2) * O + oBase + (i & 3)];
    __syncthreads();

    const float* sbase = src0 + (size_t)(nb / qdiv0) * CT * N + n0;

    v2f acc[4][2];
#pragma unroll
    for (int r = 0; r < 4; ++r) { acc[r][0] = (v2f)0.f; acc[r][1] = (v2f)0.f; }

    if (wid == 0)      conv_kloop<CA>(sbase, N, wlds, acc);
    else if (wid == 1) conv_kloop<CB>(sbase + (size_t)CA * N, N, wlds + CA * 4, acc);
    else if (wid == 2) conv_kloop<CC>(sbase + (size_t)(CA + CB) * N, N, wlds + (CA + CB) * 4, acc);
    else               conv_kloop<CD>(sbase + (size_t)(CA + CB + CC) * N, N, wlds + (CA + CB + CC) * 4, acc);

    if (wid) {
#pragma unroll
        for (int i = 0; i < 16; ++i)
            sred[(wid - 1) * 1024 + i * 64 + lane] = acc[i >> 2][(i >> 1) & 1][i & 1];
    }
    __syncthreads();
    if (wid != 0) return;
#pragma unroll
    for (int w = 0; w < 3; ++w)
#pragma unroll
        for (int i = 0; i < 16; ++i)
            acc[i >> 2][(i >> 1) & 1][i & 1] += sred[w * 1024 + i * 64 + lane];

    if constexpr (TOUT) {
#pragma unroll
        for (int j = 0; j < 4; ++j) {
            float4 t;
            t.x = acc[0][j >> 1][j & 1];
            t.y = acc[1][j >> 1][j & 1];
            t.z = acc[2][j >> 1][j & 1];
            t.w = acc[3][j >> 1][j & 1];
            *reinterpret_cast<float4*>(outp + ((size_t)nb * N + n0 + j) * O + oBase) = t;
        }
        return;
    }
    const float* bp = (ADD == 2) ? (basep + ((size_t)(nb / qdivb) * O + oBase) * N + n0) : nullptr;
#pragma unroll
    for (int ol = 0; ol < 4; ++ol) {
        int o = oBase + ol;
        float addv[4];
        if constexpr (ADD == 2) {
            float4 t = *reinterpret_cast<const float4*>(bp + (size_t)ol * N);
            addv[0] = t.x; addv[1] = t.y; addv[2] = t.z; addv[3] = t.w;
        } else if constexpr (ADD == 1) {
            float sb = shb[o];
#pragma unroll
            for (int j = 0; j < 4; ++j) addv[j] = sb;
        } else {
#pragma unroll
            for (int j = 0; j < 4; ++j) addv[j] = 0.f;
        }
        float res[4];
#pragma unroll
        for (int j = 0; j < 4; ++j) {
            float y = acc[ol][j >> 1][j & 1] + addv[j];
            if constexpr (RELU) y = fmaxf(y, 0.f);
            res[j] = y;
        }
        float4 t; t.x = res[0]; t.y = res[1]; t.z = res[2]; t.w = res[3];
        *reinterpret_cast<float4*>(outp + ((size_t)nb * O + o) * N + n0) = t;
    }
}

template <int CA, int CB, int CC, int CD, int O, bool RELU, int ADD, bool TOUT>
__global__ __launch_bounds__(256) void conv_ks4(
    const float* __restrict__ src0, int qdiv0,
    const float* __restrict__ Wt, const float* __restrict__ shb,
    const float* __restrict__ basep, int qdivb,
    float* __restrict__ outp, int N, int GX, int GY)
{
    __shared__ __align__(16) float wlds[(CA + CB + CC + CD) * 4];
    __shared__ float sred[3 * 16 * 64];
    int f = blockIdx.x;
    int J = gridDim.x >> 3;
    int j = (f & 7) * J + (f >> 3);
    int ot = j % GY; int r = j / GY;
    int nt = r % GX; int nb = r / GX;
    conv4w<CA, CB, CC, CD, O, RELU, ADD, TOUT>(
        nt, ot, nb, threadIdx.x, src0, qdiv0, Wt, shb, basep, qdivb, outp, N, wlds, sred);
}

// ---------------- single-wave conv (h1 only, CT=8) --------------------------
template <int CT, int O, int OT, bool RELU, int ADD>
__global__ __launch_bounds__(64) void conv_swz(
    const float* __restrict__ src0, int qdiv0,
    const float* __restrict__ Wt, const float* __restrict__ shb,
    const float* __restrict__ basep, int qdivb,
    float* __restrict__ outp, int N, int GX, int GY)
{
    __shared__ __align__(16) float wlds[CT * OT];
    int f = blockIdx.x;
    int J = gridDim.x >> 3;
    int j = (f & 7) * J + (f >> 3);
    int ot = j % GY; int r = j / GY;
    int nt = r % GX; int nb = r / GX;
    const int lane = threadIdx.x;
    const int oBase = ot * OT;
    const int n0 = (nt * 64 + lane) * 4;
    for (int i = lane; i < CT * OT; i += 64)
        wlds[i] = Wt[(size_t)(i / OT) * O + oBase + (i % OT)];
    __builtin_amdgcn_wave_barrier();
    const float* s0 = src0 + (size_t)(nb / qdiv0) * CT * N + n0;
    v2f acc[OT][2];
#pragma unroll
    for (int ol = 0; ol < OT; ++ol) { acc[ol][0] = (v2f)0.f; acc[ol][1] = (v2f)0.f; }
#pragma unroll
    for (int c = 0; c < CT; ++c) {
        float4 t = *reinterpret_cast<const float4*>(s0 + (size_t)c * N);
        v2f x01; x01[0] = t.x; x01[1] = t.y;
        v2f x23; x23[0] = t.z; x23[1] = t.w;
#pragma unroll
        for (int g = 0; g < OT / 4; ++g) {
            float4 wv = *reinterpret_cast<const float4*>(&wlds[c * OT + g * 4]);
            float ww[4] = {wv.x, wv.y, wv.z, wv.w};
#pragma unroll
            for (int r = 0; r < 4; ++r) {
                v2f w2; w2[0] = ww[r]; w2[1] = ww[r];
                acc[g * 4 + r][0] = __builtin_elementwise_fma(w2, x01, acc[g * 4 + r][0]);
                acc[g * 4 + r][1] = __builtin_elementwise_fma(w2, x23, acc[g * 4 + r][1]);
            }
        }
    }
    const float* bp = (ADD == 2) ? (basep + ((size_t)(nb / qdivb) * O + oBase) * N + n0) : nullptr;
#pragma unroll
    for (int ol = 0; ol < OT; ++ol) {
        int o = oBase + ol;
        float addv[4];
        if constexpr (ADD == 2) {
            float4 t = *reinterpret_cast<const float4*>(bp + (size_t)ol * N);
            addv[0] = t.x; addv[1] = t.y; addv[2] = t.z; addv[3] = t.w;
        } else if constexpr (ADD == 1) {
            float sb = shb[o];
#pragma unroll
            for (int j = 0; j < 4; ++j) addv[j] = sb;
        } else {
#pragma unroll
            for (int j = 0; j < 4; ++j) addv[j] = 0.f;
        }
        float res[4];
#pragma unroll
        for (int j = 0; j < 4; ++j) {
            float y = acc[ol][j >> 1][j & 1] + addv[j];
            if constexpr (RELU) y = fmaxf(y, 0.f);
            res[j] = y;
        }
        float4 t; t.x = res[0]; t.y = res[1]; t.z = res[2]; t.w = res[3];
        *reinterpret_cast<float4*>(outp + ((size_t)nb * O + o) * N + n0) = t;
    }
}

// per-b bases, 4-wave K-split: [0,148)=base1, [148,436)=base3
__global__ __launch_bounds__(256) void bases_kernel(
    const float* __restrict__ x, const float* __restrict__ sa1f,
    const float* __restrict__ wt1, const float* __restrict__ sb1,
    const float* __restrict__ w3c, const float* __restrict__ sh3,
    float* __restrict__ base1, float* __restrict__ base3)
{
    __shared__ __align__(16) float wlds[288 * 4];
    __shared__ float sred[3 * 16 * 64];
    const int bx = blockIdx.x, tid = threadIdx.x;
    if (bx < 148) {
        int ot = bx % 74, nb = bx / 74;
        conv4w<72, 72, 72, 72, 296, false, 1, false>(0, ot, nb, tid, x, 1, wt1, sb1, nullptr, 1, base1, 256, wlds, sred);
    } else {
        int lb = bx - 148;
        int nt = lb % 4, ot = (lb / 4) % 36, nb = lb / 144;
        conv4w<32, 32, 32, 32, 144, false, 1, false>(nt, ot, nb, tid, sa1f, 1, w3c, sh3, nullptr, 1, base3, 1024, wlds, sred);
    }
}

// ---------------- gather1: contiguous columns from g3t, c-split x2 ----------
__global__ __launch_bounds__(64) void gather_t1_kernel(
    const float* __restrict__ g3t,   // (NB, 256, 144)  n-major
    const int* __restrict__ idx, const float* __restrict__ wgt,  // (B,1024,3)
    const float* __restrict__ base3, // (B, 144, 1024)
    float* __restrict__ h3)          // (NB, 144, 1024)
{
    int f = blockIdx.x;              // 1024 blocks
    int j = (f & 7) * 128 + (f >> 3);
    int cseg = j & 1; int rest = j >> 1;
    int nb = rest >> 4, nt = rest & 15;
    int lane = threadIdx.x;
    int n = nt * 64 + lane;
    int b = nb >> 4;
    size_t nn = ((size_t)b * 1024 + n) * 3;
    int j0 = idx[nn], j1 = idx[nn + 1], j2 = idx[nn + 2];
    float w0 = wgt[nn], w1 = wgt[nn + 1], w2 = wgt[nn + 2];
    const float* gbase = g3t + (size_t)nb * 256 * 144;
    const float* p0 = gbase + (size_t)j0 * 144;
    const float* p1 = gbase + (size_t)j1 * 144;
    const float* p2 = gbase + (size_t)j2 * 144;
    const float* bb = base3 + (size_t)b * 144 * 1024 + n;
    float* ob = h3 + (size_t)nb * 144 * 1024 + n;
    const int cs = cseg * 72;
#pragma unroll 1
    for (int cc = cs; cc < cs + 72; cc += 8) {
        float4 a0 = *reinterpret_cast<const float4*>(p0 + cc);
        float4 a0b = *reinterpret_cast<const float4*>(p0 + cc + 4);
        float4 a1 = *reinterpret_cast<const float4*>(p1 + cc);
        float4 a1b = *reinterpret_cast<const float4*>(p1 + cc + 4);
        float4 a2 = *reinterpret_cast<const float4*>(p2 + cc);
        float4 a2b = *reinterpret_cast<const float4*>(p2 + cc + 4);
        float r0[8] = {a0.x, a0.y, a0.z, a0.w, a0b.x, a0b.y, a0b.z, a0b.w};
        float r1[8] = {a1.x, a1.y, a1.z, a1.w, a1b.x, a1b.y, a1b.z, a1b.w};
        float r2[8] = {a2.x, a2.y, a2.z, a2.w, a2b.x, a2b.y, a2b.z, a2b.w};
#pragma unroll
        for (int r = 0; r < 8; ++r) {
            float v = w0 * r0[r] + w1 * r1[r] + w2 * r2[r] + bb[(size_t)(cc + r) * 1024];
            ob[(size_t)(cc + r) * 1024] = fmaxf(v, 0.f);
        }
    }
}

// ---------------- h6out: gather2 + base5 + h6 + out, 2-wave static c-split --
template <int CS, int CE>
__device__ __forceinline__ void h6_partial(
    const float* __restrict__ p0, const float* __restrict__ p1,
    const float* __restrict__ p2,
    float w0, float w1, float w2, float sx, float sy, float sz,
    const float* wlds, const float* w5l, const float* sh5l,
    v2f (&acc)[18])
{
    constexpr int NCH = (CE - CS) / 8;
    float ra[8][3], rb[8][3];
    auto ld = [&](float (&r)[8][3], int c) {
        float4 a0 = *reinterpret_cast<const float4*>(p0 + c);
        float4 a0b = *reinterpret_cast<const float4*>(p0 + c + 4);
        float4 a1 = *reinterpret_cast<const float4*>(p1 + c);
        float4 a1b = *reinterpret_cast<const float4*>(p1 + c + 4);
        float4 a2 = *reinterpret_cast<const float4*>(p2 + c);
        float4 a2b = *reinterpret_cast<const float4*>(p2 + c + 4);
        r[0][0] = a0.x; r[1][0] = a0.y; r[2][0] = a0.z; r[3][0] = a0.w;
        r[4][0] = a0b.x; r[5][0] = a0b.y; r[6][0] = a0b.z; r[7][0] = a0b.w;
        r[0][1] = a1.x; r[1][1] = a1.y; r[2][1] = a1.z; r[3][1] = a1.w;
        r[4][1] = a1b.x; r[5][1] = a1b.y; r[6][1] = a1b.z; r[7][1] = a1b.w;
        r[0][2] = a2.x; r[1][2] = a2.y; r[2][2] = a2.z; r[3][2] = a2.w;
        r[4][2] = a2b.x; r[5][2] = a2b.y; r[6][2] = a2b.z; r[7][2] = a2b.w;
    };
    auto cp = [&](const float (&r)[8][3], int c) {
#pragma unroll
        for (int q = 0; q < 8; ++q) {
            int cc = c + q;
            float base = w5l[cc] * sx + w5l[72 + cc] * sy + w5l[144 + cc] * sz + sh5l[cc];
            float xv = fmaxf(w0 * r[q][0] + w1 * r[q][1] + w2 * r[q][2] + base, 0.f);
            v2f xv2; xv2[0] = xv; xv2[1] = xv;
#pragma unroll
            for (int g = 0; g < 9; ++g) {
                float4 wv = *reinterpret_cast<const float4*>(&wlds[cc * 36 + g * 4]);
                v2f wa; wa[0] = wv.x; wa[1] = wv.y;
                v2f wb; wb[0] = wv.z; wb[1] = wv.w;
                acc[g * 2 + 0] = __builtin_elementwise_fma(wa, xv2, acc[g * 2 + 0]);
                acc[g * 2 + 1] = __builtin_elementwise_fma(wb, xv2, acc[g * 2 + 1]);
            }
        }
    };
    ld(ra, CS);
#pragma unroll
    for (int i = 0; i < NCH; ++i) {
        const int c = CS + i * 8;
        if ((i & 1) == 0) {
            if (i + 1 < NCH) ld(rb, c + 8);
            cp(ra, c);
            if (i + 2 < NCH) ld(ra, c + 16);
        } else {
            cp(rb, c);
            if (i + 2 < NCH) ld(rb, c + 16);
        }
    }
}

__global__ __launch_bounds__(128) void h6out_kernel(
    const float* __restrict__ g5t,   // (NB, 1024, 72)  n-major
    const int* __restrict__ idx, const float* __restrict__ wgt,  // (B,4096,3)
    const float* __restrict__ sa0,   // (B, 3, 4096)
    const float* __restrict__ w5c, const float* __restrict__ sh5,
    const float* __restrict__ Wt6, const float* __restrict__ shb6,
    const float* __restrict__ wout, const float* __restrict__ bout,
    float* __restrict__ outp)        // (NB, 4096)
{
    __shared__ __align__(16) float wlds[72 * 36];
    __shared__ float w5l[3 * 72];
    __shared__ float sh5l[72], ow[36], sh6l[36];
    __shared__ float sred[36 * 64];
    const int tid = threadIdx.x;
    for (int i = tid; i < 72 * 36; i += 128) wlds[i] = Wt6[i];
    for (int i = tid; i < 216; i += 128) w5l[i] = w5c[i];
    if (tid < 72) sh5l[tid] = sh5[tid];
    if (tid < 36) { ow[tid] = wout[tid]; sh6l[tid] = shb6[tid]; }
    __syncthreads();
    int f = blockIdx.x;
    int j = (f & 7) * ((int)gridDim.x >> 3) + (f >> 3);
    const int nb = j >> 6;
    const int nt = j & 63;
    const int wid = tid >> 6, lane = tid & 63;
    const int n = nt * 64 + lane;
    const int b = nb >> 4;
    size_t nn = ((size_t)b * 4096 + n) * 3;
    const int j0 = idx[nn], j1 = idx[nn + 1], j2 = idx[nn + 2];
    const float w0 = wgt[nn], w1 = wgt[nn + 1], w2 = wgt[nn + 2];
    const float* gbase = g5t + (size_t)nb * 1024 * 72;
    const float* p0 = gbase + (size_t)j0 * 72;
    const float* p1 = gbase + (size_t)j1 * 72;
    const float* p2 = gbase + (size_t)j2 * 72;
    const float* s0 = sa0 + (size_t)b * 3 * 4096 + n;
    const float sx = s0[0], sy = s0[4096], sz = s0[8192];

    v2f acc[18];
#pragma unroll
    for (int o = 0; o < 18; ++o) acc[o] = (v2f)0.f;

    if (wid == 0) h6_partial<0, 40>(p0, p1, p2, w0, w1, w2, sx, sy, sz, wlds, w5l, sh5l, acc);
    else          h6_partial<40, 72>(p0, p1, p2, w0, w1, w2, sx, sy, sz, wlds, w5l, sh5l, acc);

    if (wid == 1) {
#pragma unroll
        for (int i = 0; i < 36; ++i) sred[i * 64 + lane] = acc[i >> 1][i & 1];
    }
    __syncthreads();
    if (wid != 0) return;
#pragma unroll
    for (int i = 0; i < 36; ++i) acc[i >> 1][i & 1] += sred[i * 64 + lane];

    float r = bout[0];
#pragma unroll
    for (int o = 0; o < 36; ++o) r += ow[o] * fmaxf(acc[o >> 1][o & 1] + sh6l[o], 0.f);
    outp[(size_t)nb * 4096 + n] = r;
}

extern "C" void kernel_launch(void* const* d_in, const int* in_sizes, int n_in,
                              void* d_out, int out_size, void* d_ws, size_t ws_size,
                              hipStream_t stream) {
    const int B = 2, Q = 16, N0 = 4096, N1 = 1024, N2 = 256;
    const int I1 = 144;
    const int NB = B * Q;  // 32

    const float* x     = (const float*)d_in[0];
    const float* mask  = (const float*)d_in[1];
    const float* sa0f  = (const float*)d_in[2];
    const float* sa1f  = (const float*)d_in[3];
    const float* xyz0  = (const float*)d_in[4];
    const float* xyz1  = (const float*)d_in[5];
    const float* xyz2  = (const float*)d_in[6];

    float* ws = (float*)d_ws;
    size_t off = 0;
    auto alloc = [&](size_t n) { size_t p = off; off += (n + 15) & ~(size_t)15; return p; };

    size_t wgt1  = alloc((size_t)B * N1 * 3);
    size_t wgt2  = alloc((size_t)B * N0 * 3);
    size_t idx1  = alloc((size_t)B * N1 * 3);
    size_t idx2  = alloc((size_t)B * N0 * 3);
    size_t slotA = alloc((size_t)NB * 296 * N2);  // h1 / g3t / h4
    size_t slotB = alloc((size_t)NB * I1 * N1);   // h2 / h3 / g5t
    size_t base1 = alloc((size_t)B * 296 * N2);
    size_t base3 = alloc((size_t)B * I1 * N1);
    size_t wt1 = alloc(296 * 296), sb1 = alloc(296);
    size_t wt2 = alloc(296 * 144), sb2 = alloc(144);
    size_t wt3 = alloc(288 * 144), sb3 = alloc(144);
    size_t wt4 = alloc(144 * 72),  sb4 = alloc(72);
    size_t wt5 = alloc(144 * 72),  sb5 = alloc(72);
    size_t wt6 = alloc(72 * 36),   sb6 = alloc(36);
    size_t w3c = alloc(128 * 144), sh3 = alloc(144);
    size_t w5c = alloc(3 * 72),    sh5 = alloc(72);
    (void)ws_size; (void)in_sizes; (void)n_in;

    auto din = [&](int i) { return (const float*)d_in[i]; };

    HeadArgs ha;
    ha.l[0] = { din(7),  din(8),  din(9),  ws + wt1, ws + sb1, 296, 296 };
    ha.l[1] = { din(10), din(11), din(12), ws + wt2, ws + sb2, 144, 296 };
    ha.l[2] = { din(17), din(18), din(19), ws + wt3, ws + sb3, 144, 288 };
    ha.l[3] = { din(20), din(21), din(22), ws + wt4, ws + sb4, 72, 144 };
    ha.l[4] = { din(23), din(24), din(25), ws + wt5, ws + sb5, 72, 144 };
    ha.l[5] = { din(26), din(27), din(28), ws + wt6, ws + sb6, 36, 72 };
    ha.a2w = din(15); ha.a2b = din(16); ha.w3 = din(17); ha.b3 = din(18); ha.bn3 = din(19);
    ha.w3c = ws + w3c; ha.sh3 = ws + sh3;
    ha.a1w = din(13); ha.a1b = din(14); ha.w5 = din(23); ha.b5 = din(24); ha.bn5 = din(25);
    ha.w5c = ws + w5c; ha.sh5 = ws + sh5;
    ha.xyz0 = xyz0; ha.xyz1 = xyz1; ha.xyz2 = xyz2;
    ha.idx1 = (int*)(ws + idx1); ha.wgt1 = ws + wgt1;
    ha.idx2 = (int*)(ws + idx2); ha.wgt2 = ws + wgt2;
    head_kernel<<<dim3(171 + 64 + 256), 256, 0, stream>>>(ha);

    // per-b bases (base1 | base3), 4-wave K-split
    bases_kernel<<<dim3(436), 256, 0, stream>>>(
        x, sa1f, ws + wt1, ws + sb1, ws + w3c, ws + sh3, ws + base1, ws + base3);

    // h1 = ReLU(W1[:,288:] @ mask + base1) -> slotA   [2368 1-wave blocks]
    conv_swz<8, 296, 4, true, 2><<<dim3(2368), 64, 0, stream>>>(
        mask, 1, ws + wt1 + 288 * 296, ws + sb1, ws + base1, Q, ws + slotA, N2, 1, 74);

    // h2 -> slotB   [1152 blocks x 4 waves, K-split 80+72+72+72]
    conv_ks4<80, 72, 72, 72, 144, true, 1, false><<<dim3(1152), 256, 0, stream>>>(
        ws + slotA, 1, ws + wt2, ws + sb2, nullptr, 1, ws + slotB, N2, 1, 36);

    // g3t = (W3a @ h2)^T  (NB, 256, 144) -> slotA   [1152 blocks, K 36x4]
    conv_ks4<36, 36, 36, 36, 144, false, 0, true><<<dim3(1152), 256, 0, stream>>>(
        ws + slotB, 1, ws + wt3, ws + sb3, nullptr, 1, ws + slotA, N2, 1, 36);

    // h3 = ReLU(gather(g3t) + base3) -> slotB   [1024 blocks, c-split x2]
    gather_t1_kernel<<<dim3(1024), 64, 0, stream>>>(
        ws + slotA, (const int*)(ws + idx1), ws + wgt1, ws + base3, ws + slotB);

    // h4 = ReLU(W4 @ h3 + shb4) -> slotA   [2304 blocks, K 36x4]
    conv_ks4<36, 36, 36, 36, 72, true, 1, false><<<dim3(2304), 256, 0, stream>>>(
        ws + slotB, 1, ws + wt4, ws + sb4, nullptr, 1, ws + slotA, N1, 4, 18);

    // g5t = (W5a @ h4)^T  (NB, 1024, 72) -> slotB   [2304 blocks, K 20+20+16+16]
    conv_ks4<20, 20, 16, 16, 72, false, 0, true><<<dim3(2304), 256, 0, stream>>>(
        ws + slotA, 1, ws + wt5, ws + sb5, nullptr, 1, ws + slotB, N1, 4, 18);

    // fused gather2 + base5 + h6 + out -> d_out   [2048 blocks x 2 waves, c-split]
    h6out_kernel<<<dim3(2048), 128, 0, stream>>>(
        ws + slotB, (const int*)(ws + idx2), ws + wgt2, sa0f,
        ws + w5c, ws + sh5, ws + wt6, ws + sb6, din(29), din(30), (float*)d_out);
}

// Round 20
// 156.491 us; speedup vs baseline: 1.0862x; 1.0862x over previous
//
#include <hip/hip_runtime.h>

#define EPS_BN 1e-5f
typedef float v2f __attribute__((ext_vector_type(2)));

// ---------------- prep/compose + three_nn merged (r11-verified) ----------
struct LayerDesc {
    const float* W; const float* b; const float* bn;
    float* wt; float* shb; int O; int C;
};
struct HeadArgs {
    LayerDesc l[6];
    const float* a2w; const float* a2b; const float* w3; const float* b3; const float* bn3;
    float* w3c; float* sh3;
    const float* a1w; const float* a1b; const float* w5; const float* b5; const float* bn5;
    float* w5c; float* sh5;
    const float* xyz0; const float* xyz1; const float* xyz2;
    int* idx1; float* wgt1; int* idx2; float* wgt2;
};

__global__ __launch_bounds__(256) void head_kernel(HeadArgs a) {
    const int bx = blockIdx.x, tid = threadIdx.x;
    if (bx < 96) {
        LayerDesc d = a.l[bx / 16];
        int sub = bx % 16;
        int total = d.O * d.C;
        for (int i = sub * 256 + tid; i < total; i += 16 * 256) {
            int c = i / d.O, o = i - (i / d.O) * d.O;
            float sc = 1.f;
            if (d.bn) { float g = d.bn[o], v = d.bn[3 * d.O + o]; sc = g * rsqrtf(v + EPS_BN); }
            d.wt[i] = d.W[(size_t)o * d.C + c] * sc;
        }
        for (int o = sub * 256 + tid; o < d.O; o += 16 * 256) {
            float sc = 1.f, sh = 0.f;
            if (d.bn) {
                float g = d.bn[o], be = d.bn[d.O + o], m = d.bn[2 * d.O + o], v = d.bn[3 * d.O + o];
                sc = g * rsqrtf(v + EPS_BN); sh = be - m * sc;
            }
            d.shb[o] = d.b[o] * sc + sh;
        }
        return;
    } else if (bx < 169) {
        int e = (bx - 96) * 256 + tid;
        if (e < 128 * 144) {
            int k = e / 144, o = e - (e / 144) * 144;
            float sc = a.bn3[o] * rsqrtf(a.bn3[3 * 144 + o] + EPS_BN);
            float s = 0.f;
            for (int c = 0; c < 144; ++c)
                s += a.a2w[c * 128 + k] * a.w3[(size_t)o * 288 + 144 + c];
            a.w3c[k * 144 + o] = s * sc;
        } else if (e < 128 * 144 + 144) {
            int o = e - 128 * 144;
            float g = a.bn3[o], be = a.bn3[144 + o], m = a.bn3[2 * 144 + o], v = a.bn3[3 * 144 + o];
            float sc = g * rsqrtf(v + EPS_BN);
            float s = 0.f;
            for (int c = 0; c < 144; ++c) s += a.w3[(size_t)o * 288 + 144 + c] * a.a2b[c];
            a.sh3[o] = (s + a.b3[o] - m) * sc + be;
        }
        return;
    } else if (bx < 171) {
        int e = (bx - 169) * 256 + tid;
        if (e < 3 * 72) {
            int k = e / 72, o = e - (e / 72) * 72;
            float sc = a.bn5[o] * rsqrtf(a.bn5[3 * 72 + o] + EPS_BN);
            float s = 0.f;
            for (int c = 0; c < 72; ++c)
                s += a.a1w[c * 3 + k] * a.w5[(size_t)o * 144 + 72 + c];
            a.w5c[k * 72 + o] = s * sc;
        } else if (e < 3 * 72 + 72) {
            int o = e - 3 * 72;
            float g = a.bn5[o], be = a.bn5[72 + o], m = a.bn5[2 * 72 + o], v = a.bn5[3 * 72 + o];
            float sc = g * rsqrtf(v + EPS_BN);
            float s = 0.f;
            for (int c = 0; c < 72; ++c) s += a.w5[(size_t)o * 144 + 72 + c] * a.a1b[c];
            a.sh5[o] = (s + a.b5[o] - m) * sc + be;
        }
        return;
    }
    // ---- three_nn: 256 threads = 32 unknowns x 8 segments ----
    const int NSEG = 8;
    __shared__ float kl[3 * 1024];
    __shared__ float sd[NSEG][32][3];
    __shared__ int   si[NSEG][32][3];
    const float* unknown; const float* known;
    int Nu, Nk, blk, b; int* idx; float* wgt;
    int t = bx - 171;
    if (t < 64) {
        unknown = a.xyz1; known = a.xyz2; Nu = 1024; Nk = 256;
        b = t >> 5; blk = t & 31; idx = a.idx1; wgt = a.wgt1;
    } else {
        t -= 64;
        unknown = a.xyz0; known = a.xyz1; Nu = 4096; Nk = 1024;
        b = t >> 7; blk = t & 127; idx = a.idx2; wgt = a.wgt2;
    }
    for (int i = tid; i < Nk * 3; i += 256) kl[i] = known[(size_t)b * Nk * 3 + i];
    __syncthreads();
    const int u   = tid & 31;
    const int seg = tid >> 5;
    const int n   = blk * 32 + u;
    const float* up = unknown + ((size_t)b * Nu + n) * 3;
    const float ux = up[0], uy = up[1], uz = up[2];
    float d0 = 1e30f, d1 = 1e30f, d2 = 1e30f;
    int i0 = 0, i1 = 0, i2 = 0;
    const int klo = seg * (Nk / NSEG), khi = klo + Nk / NSEG;
    for (int k = klo; k < khi; ++k) {
        float dx = __fsub_rn(ux, kl[3 * k + 0]);
        float dy = __fsub_rn(uy, kl[3 * k + 1]);
        float dz = __fsub_rn(uz, kl[3 * k + 2]);
        float d = __fadd_rn(__fadd_rn(__fmul_rn(dx, dx), __fmul_rn(dy, dy)), __fmul_rn(dz, dz));
        if (d < d0)      { d2 = d1; i2 = i1; d1 = d0; i1 = i0; d0 = d; i0 = k; }
        else if (d < d1) { d2 = d1; i2 = i1; d1 = d;  i1 = k; }
        else if (d < d2) { d2 = d;  i2 = k; }
    }
    sd[seg][u][0] = d0; sd[seg][u][1] = d1; sd[seg][u][2] = d2;
    si[seg][u][0] = i0; si[seg][u][1] = i1; si[seg][u][2] = i2;
    __syncthreads();
    if (tid < 32) {
        float m0 = 1e30f, m1 = 1e30f, m2 = 1e30f;
        int j0 = 0, j1 = 0, j2 = 0;
        for (int s = 0; s < NSEG; ++s)
            for (int c = 0; c < 3; ++c) {
                float d = sd[s][u][c];
                int ii = si[s][u][c];
                if (d < m0)      { m2 = m1; j2 = j1; m1 = m0; j1 = j0; m0 = d; j0 = ii; }
                else if (d < m1) { m2 = m1; j2 = j1; m1 = d;  j1 = ii; }
                else if (d < m2) { m2 = d;  j2 = ii; }
            }
        float w0 = 1.f / (m0 + 1e-8f), w1 = 1.f / (m1 + 1e-8f), w2 = 1.f / (m2 + 1e-8f);
        float s = w0 + w1 + w2;
        size_t base = ((size_t)b * Nu + n) * 3;
        idx[base + 0] = j0; idx[base + 1] = j1; idx[base + 2] = j2;
        wgt[base + 0] = w0 / s; wgt[base + 1] = w1 / s; wgt[base + 2] = w2 / s;
    }
}

// ---------------- pipelined K-loop for one wave, OT=4 ----------------------
template <int CTW>
__device__ __forceinline__ void conv_kloop(
    const float* __restrict__ s0, int N, const float* wldsw, v2f (&acc)[4][2])
{
    static_assert(CTW % 8 == 0 || CTW % 8 == 4, "CT tail");
    auto loadrow = [&](float (&x)[4], int c) {
        float4 t = *reinterpret_cast<const float4*>(s0 + (size_t)c * N);
        x[0] = t.x; x[1] = t.y; x[2] = t.z; x[3] = t.w;
    };
    auto comprow = [&](const float (&x)[4], int c) {
        v2f x01; x01[0] = x[0]; x01[1] = x[1];
        v2f x23; x23[0] = x[2]; x23[1] = x[3];
        float4 wv = *reinterpret_cast<const float4*>(wldsw + c * 4);
        float ww[4] = {wv.x, wv.y, wv.z, wv.w};
#pragma unroll
        for (int r = 0; r < 4; ++r) {
            v2f w2; w2[0] = ww[r]; w2[1] = ww[r];
            acc[r][0] = __builtin_elementwise_fma(w2, x01, acc[r][0]);
            acc[r][1] = __builtin_elementwise_fma(w2, x23, acc[r][1]);
        }
    };
    auto loadg = [&](float (&buf)[4][4], int c) {
#pragma unroll
        for (int q = 0; q < 4; ++q) loadrow(buf[q], c + q);
    };
    auto compg = [&](const float (&buf)[4][4], int c) {
#pragma unroll
        for (int q = 0; q < 4; ++q) comprow(buf[q], c + q);
    };
    float xa[4][4], xb[4][4];
    loadg(xa, 0); loadg(xb, 4);
    int c = 0;
#pragma unroll 1
    for (; c + 16 <= CTW; c += 8) {
        compg(xa, c);     loadg(xa, c + 8);
        compg(xb, c + 4); loadg(xb, c + 12);
    }
    compg(xa, c);
    if constexpr (CTW % 8 == 4) {
        loadg(xa, c + 8);
        compg(xb, c + 4);
        compg(xa, c + 8);
    } else {
        compg(xb, c + 4);
    }
}

// ---------------- 4-wave K-split conv body (256 threads/block) -------------
template <int CA, int CB, int CC, int CD, int O, bool RELU, int ADD, bool TOUT>
__device__ __forceinline__ void conv4w(
    int nt, int ot, int nb, int tid,
    const float* __restrict__ src0, int qdiv0,
    const float* __restrict__ Wt, const float* __restrict__ shb,
    const float* __restrict__ basep, int qdivb,
    float* __restrict__ outp, int N, float* wlds, float* sred)
{
    constexpr int CT = CA + CB + CC + CD;
    const int wid = tid >> 6, lane = tid & 63;
    const int oBase = ot * 4;
    const int n0 = (nt * 64 + lane) * 4;

    for (int i = tid; i < CT * 4; i += 256)
        wlds[i] = Wt[(size_t)(i >> 2) * O + oBase + (i & 3)];
    __syncthreads();

    const float* sbase = src0 + (size_t)(nb / qdiv0) * CT * N + n0;

    v2f acc[4][2];
#pragma unroll
    for (int r = 0; r < 4; ++r) { acc[r][0] = (v2f)0.f; acc[r][1] = (v2f)0.f; }

    if (wid == 0)      conv_kloop<CA>(sbase, N, wlds, acc);
    else if (wid == 1) conv_kloop<CB>(sbase + (size_t)CA * N, N, wlds + CA * 4, acc);
    else if (wid == 2) conv_kloop<CC>(sbase + (size_t)(CA + CB) * N, N, wlds + (CA + CB) * 4, acc);
    else               conv_kloop<CD>(sbase + (size_t)(CA + CB + CC) * N, N, wlds + (CA + CB + CC) * 4, acc);

    if (wid) {
#pragma unroll
        for (int i = 0; i < 16; ++i)
            sred[(wid - 1) * 1024 + i * 64 + lane] = acc[i >> 2][(i >> 1) & 1][i & 1];
    }
    __syncthreads();
    if (wid != 0) return;
#pragma unroll
    for (int w = 0; w < 3; ++w)
#pragma unroll
        for (int i = 0; i < 16; ++i)
            acc[i >> 2][(i >> 1) & 1][i & 1] += sred[w * 1024 + i * 64 + lane];

    if constexpr (TOUT) {
#pragma unroll
        for (int j = 0; j < 4; ++j) {
            float4 t;
            t.x = acc[0][j >> 1][j & 1];
            t.y = acc[1][j >> 1][j & 1];
            t.z = acc[2][j >> 1][j & 1];
            t.w = acc[3][j >> 1][j & 1];
            *reinterpret_cast<float4*>(outp + ((size_t)nb * N + n0 + j) * O + oBase) = t;
        }
        return;
    }
    const float* bp = (ADD == 2) ? (basep + ((size_t)(nb / qdivb) * O + oBase) * N + n0) : nullptr;
#pragma unroll
    for (int ol = 0; ol < 4; ++ol) {
        int o = oBase + ol;
        float addv[4];
        if constexpr (ADD == 2) {
            float4 t = *reinterpret_cast<const float4*>(bp + (size_t)ol * N);
            addv[0] = t.x; addv[1] = t.y; addv[2] = t.z; addv[3] = t.w;
        } else if constexpr (ADD == 1) {
            float sb = shb[o];
#pragma unroll
            for (int j = 0; j < 4; ++j) addv[j] = sb;
        } else {
#pragma unroll
            for (int j = 0; j < 4; ++j) addv[j] = 0.f;
        }
        float res[4];
#pragma unroll
        for (int j = 0; j < 4; ++j) {
            float y = acc[ol][j >> 1][j & 1] + addv[j];
            if constexpr (RELU) y = fmaxf(y, 0.f);
            res[j] = y;
        }
        float4 t; t.x = res[0]; t.y = res[1]; t.z = res[2]; t.w = res[3];
        *reinterpret_cast<float4*>(outp + ((size_t)nb * O + o) * N + n0) = t;
    }
}

template <int CA, int CB, int CC, int CD, int O, bool RELU, int ADD, bool TOUT>
__global__ __launch_bounds__(256) void conv_ks4(
    const float* __restrict__ src0, int qdiv0,
    const float* __restrict__ Wt, const float* __restrict__ shb,
    const float* __restrict__ basep, int qdivb,
    float* __restrict__ outp, int N, int GX, int GY)
{
    __shared__ __align__(16) float wlds[(CA + CB + CC + CD) * 4];
    __shared__ float sred[3 * 16 * 64];
    int f = blockIdx.x;
    int J = gridDim.x >> 3;
    int j = (f & 7) * J + (f >> 3);
    int ot = j % GY; int r = j / GY;
    int nt = r % GX; int nb = r / GX;
    conv4w<CA, CB, CC, CD, O, RELU, ADD, TOUT>(
        nt, ot, nb, threadIdx.x, src0, qdiv0, Wt, shb, basep, qdivb, outp, N, wlds, sred);
}

// ---------------- single-wave conv (h1 only, CT=8) --------------------------
template <int CT, int O, int OT, bool RELU, int ADD>
__global__ __launch_bounds__(64) void conv_swz(
    const float* __restrict__ src0, int qdiv0,
    const float* __restrict__ Wt, const float* __restrict__ shb,
    const float* __restrict__ basep, int qdivb,
    float* __restrict__ outp, int N, int GX, int GY)
{
    __shared__ __align__(16) float wlds[CT * OT];
    int f = blockIdx.x;
    int J = gridDim.x >> 3;
    int j = (f & 7) * J + (f >> 3);
    int ot = j % GY; int r = j / GY;
    int nt = r % GX; int nb = r / GX;
    const int lane = threadIdx.x;
    const int oBase = ot * OT;
    const int n0 = (nt * 64 + lane) * 4;
    for (int i = lane; i < CT * OT; i += 64)
        wlds[i] = Wt[(size_t)(i / OT) * O + oBase + (i % OT)];
    __builtin_amdgcn_wave_barrier();
    const float* s0 = src0 + (size_t)(nb / qdiv0) * CT * N + n0;
    v2f acc[OT][2];
#pragma unroll
    for (int ol = 0; ol < OT; ++ol) { acc[ol][0] = (v2f)0.f; acc[ol][1] = (v2f)0.f; }
#pragma unroll
    for (int c = 0; c < CT; ++c) {
        float4 t = *reinterpret_cast<const float4*>(s0 + (size_t)c * N);
        v2f x01; x01[0] = t.x; x01[1] = t.y;
        v2f x23; x23[0] = t.z; x23[1] = t.w;
#pragma unroll
        for (int g = 0; g < OT / 4; ++g) {
            float4 wv = *reinterpret_cast<const float4*>(&wlds[c * OT + g * 4]);
            float ww[4] = {wv.x, wv.y, wv.z, wv.w};
#pragma unroll
            for (int r = 0; r < 4; ++r) {
                v2f w2; w2[0] = ww[r]; w2[1] = ww[r];
                acc[g * 4 + r][0] = __builtin_elementwise_fma(w2, x01, acc[g * 4 + r][0]);
                acc[g * 4 + r][1] = __builtin_elementwise_fma(w2, x23, acc[g * 4 + r][1]);
            }
        }
    }
    const float* bp = (ADD == 2) ? (basep + ((size_t)(nb / qdivb) * O + oBase) * N + n0) : nullptr;
#pragma unroll
    for (int ol = 0; ol < OT; ++ol) {
        int o = oBase + ol;
        float addv[4];
        if constexpr (ADD == 2) {
            float4 t = *reinterpret_cast<const float4*>(bp + (size_t)ol * N);
            addv[0] = t.x; addv[1] = t.y; addv[2] = t.z; addv[3] = t.w;
        } else if constexpr (ADD == 1) {
            float sb = shb[o];
#pragma unroll
            for (int j = 0; j < 4; ++j) addv[j] = sb;
        } else {
#pragma unroll
            for (int j = 0; j < 4; ++j) addv[j] = 0.f;
        }
        float res[4];
#pragma unroll
        for (int j = 0; j < 4; ++j) {
            float y = acc[ol][j >> 1][j & 1] + addv[j];
            if constexpr (RELU) y = fmaxf(y, 0.f);
            res[j] = y;
        }
        float4 t; t.x = res[0]; t.y = res[1]; t.z = res[2]; t.w = res[3];
        *reinterpret_cast<float4*>(outp + ((size_t)nb * O + o) * N + n0) = t;
    }
}

// per-b bases, 4-wave K-split: [0,148)=base1, [148,436)=base3
__global__ __launch_bounds__(256) void bases_kernel(
    const float* __restrict__ x, const float* __restrict__ sa1f,
    const float* __restrict__ wt1, const float* __restrict__ sb1,
    const float* __restrict__ w3c, const float* __restrict__ sh3,
    float* __restrict__ base1, float* __restrict__ base3)
{
    __shared__ __align__(16) float wlds[288 * 4];
    __shared__ float sred[3 * 16 * 64];
    const int bx = blockIdx.x, tid = threadIdx.x;
    if (bx < 148) {
        int ot = bx % 74, nb = bx / 74;
        conv4w<72, 72, 72, 72, 296, false, 1, false>(0, ot, nb, tid, x, 1, wt1, sb1, nullptr, 1, base1, 256, wlds, sred);
    } else {
        int lb = bx - 148;
        int nt = lb % 4, ot = (lb / 4) % 36, nb = lb / 144;
        conv4w<32, 32, 32, 32, 144, false, 1, false>(nt, ot, nb, tid, sa1f, 1, w3c, sh3, nullptr, 1, base3, 1024, wlds, sred);
    }
}

// ---------------- gather1: contiguous columns from g3t, c-split x2 ----------
__global__ __launch_bounds__(64) void gather_t1_kernel(
    const float* __restrict__ g3t,   // (NB, 256, 144)  n-major
    const int* __restrict__ idx, const float* __restrict__ wgt,  // (B,1024,3)
    const float* __restrict__ base3, // (B, 144, 1024)
    float* __restrict__ h3)          // (NB, 144, 1024)
{
    int f = blockIdx.x;              // 1024 blocks
    int j = (f & 7) * 128 + (f >> 3);
    int cseg = j & 1; int rest = j >> 1;
    int nb = rest >> 4, nt = rest & 15;
    int lane = threadIdx.x;
    int n = nt * 64 + lane;
    int b = nb >> 4;
    size_t nn = ((size_t)b * 1024 + n) * 3;
    int j0 = idx[nn], j1 = idx[nn + 1], j2 = idx[nn + 2];
    float w0 = wgt[nn], w1 = wgt[nn + 1], w2 = wgt[nn + 2];
    const float* gbase = g3t + (size_t)nb * 256 * 144;
    const float* p0 = gbase + (size_t)j0 * 144;
    const float* p1 = gbase + (size_t)j1 * 144;
    const float* p2 = gbase + (size_t)j2 * 144;
    const float* bb = base3 + (size_t)b * 144 * 1024 + n;
    float* ob = h3 + (size_t)nb * 144 * 1024 + n;
    const int cs = cseg * 72;
#pragma unroll 1
    for (int cc = cs; cc < cs + 72; cc += 8) {
        float4 a0 = *reinterpret_cast<const float4*>(p0 + cc);
        float4 a0b = *reinterpret_cast<const float4*>(p0 + cc + 4);
        float4 a1 = *reinterpret_cast<const float4*>(p1 + cc);
        float4 a1b = *reinterpret_cast<const float4*>(p1 + cc + 4);
        float4 a2 = *reinterpret_cast<const float4*>(p2 + cc);
        float4 a2b = *reinterpret_cast<const float4*>(p2 + cc + 4);
        float r0[8] = {a0.x, a0.y, a0.z, a0.w, a0b.x, a0b.y, a0b.z, a0b.w};
        float r1[8] = {a1.x, a1.y, a1.z, a1.w, a1b.x, a1b.y, a1b.z, a1b.w};
        float r2[8] = {a2.x, a2.y, a2.z, a2.w, a2b.x, a2b.y, a2b.z, a2b.w};
#pragma unroll
        for (int r = 0; r < 8; ++r) {
            float v = w0 * r0[r] + w1 * r1[r] + w2 * r2[r] + bb[(size_t)(cc + r) * 1024];
            ob[(size_t)(cc + r) * 1024] = fmaxf(v, 0.f);
        }
    }
}

// ---------------- fused gather2 + base5 + h6 + out (r18-verified, 1 wave) ---
__global__ __launch_bounds__(64) void h6out_kernel(
    const float* __restrict__ g5t,   // (NB, 1024, 72)  n-major
    const int* __restrict__ idx, const float* __restrict__ wgt,  // (B,4096,3)
    const float* __restrict__ sa0,   // (B, 3, 4096)
    const float* __restrict__ w5c, const float* __restrict__ sh5,
    const float* __restrict__ Wt6, const float* __restrict__ shb6,
    const float* __restrict__ wout, const float* __restrict__ bout,
    float* __restrict__ outp)        // (NB, 4096)
{
    __shared__ __align__(16) float wlds[72 * 36];
    __shared__ float w5l[3 * 72];
    __shared__ float sh5l[72], ow[36], sh6l[36];
    const int tid = threadIdx.x;
    for (int i = tid; i < 72 * 36; i += 64) wlds[i] = Wt6[i];
    for (int i = tid; i < 216; i += 64) w5l[i] = w5c[i];
    for (int i = tid; i < 72; i += 64) sh5l[i] = sh5[i];
    if (tid < 36) { ow[tid] = wout[tid]; sh6l[tid] = shb6[tid]; }
    __syncthreads();
    int f = blockIdx.x;
    int j = (f & 7) * ((int)gridDim.x >> 3) + (f >> 3);
    const int nb = j >> 6;
    const int nt = j & 63;
    const int n = nt * 64 + tid;
    const int b = nb >> 4;
    size_t nn = ((size_t)b * 4096 + n) * 3;
    const int j0 = idx[nn], j1 = idx[nn + 1], j2 = idx[nn + 2];
    const float w0 = wgt[nn], w1 = wgt[nn + 1], w2 = wgt[nn + 2];
    const float* gbase = g5t + (size_t)nb * 1024 * 72;
    const float* p0 = gbase + (size_t)j0 * 72;
    const float* p1 = gbase + (size_t)j1 * 72;
    const float* p2 = gbase + (size_t)j2 * 72;
    const float* s0 = sa0 + (size_t)b * 3 * 4096 + n;
    const float sx = s0[0], sy = s0[4096], sz = s0[8192];

    v2f acc[18];
#pragma unroll
    for (int o = 0; o < 18; ++o) acc[o] = (v2f)0.f;

    float ra[8][3], rb[8][3];
    auto ld = [&](float (&r)[8][3], int c) {
        float4 a0 = *reinterpret_cast<const float4*>(p0 + c);
        float4 a0b = *reinterpret_cast<const float4*>(p0 + c + 4);
        float4 a1 = *reinterpret_cast<const float4*>(p1 + c);
        float4 a1b = *reinterpret_cast<const float4*>(p1 + c + 4);
        float4 a2 = *reinterpret_cast<const float4*>(p2 + c);
        float4 a2b = *reinterpret_cast<const float4*>(p2 + c + 4);
        r[0][0] = a0.x; r[1][0] = a0.y; r[2][0] = a0.z; r[3][0] = a0.w;
        r[4][0] = a0b.x; r[5][0] = a0b.y; r[6][0] = a0b.z; r[7][0] = a0b.w;
        r[0][1] = a1.x; r[1][1] = a1.y; r[2][1] = a1.z; r[3][1] = a1.w;
        r[4][1] = a1b.x; r[5][1] = a1b.y; r[6][1] = a1b.z; r[7][1] = a1b.w;
        r[0][2] = a2.x; r[1][2] = a2.y; r[2][2] = a2.z; r[3][2] = a2.w;
        r[4][2] = a2b.x; r[5][2] = a2b.y; r[6][2] = a2b.z; r[7][2] = a2b.w;
    };
    auto cp = [&](const float (&r)[8][3], int c) {
#pragma unroll
        for (int q = 0; q < 8; ++q) {
            int cc = c + q;
            float base = w5l[cc] * sx + w5l[72 + cc] * sy + w5l[144 + cc] * sz + sh5l[cc];
            float xv = fmaxf(w0 * r[q][0] + w1 * r[q][1] + w2 * r[q][2] + base, 0.f);
            v2f xv2; xv2[0] = xv; xv2[1] = xv;
#pragma unroll
            for (int g = 0; g < 9; ++g) {
                float4 wv = *reinterpret_cast<const float4*>(&wlds[cc * 36 + g * 4]);
                v2f wa; wa[0] = wv.x; wa[1] = wv.y;
                v2f wb; wb[0] = wv.z; wb[1] = wv.w;
                acc[g * 2 + 0] = __builtin_elementwise_fma(wa, xv2, acc[g * 2 + 0]);
                acc[g * 2 + 1] = __builtin_elementwise_fma(wb, xv2, acc[g * 2 + 1]);
            }
        }
    };
    ld(ra, 0); ld(rb, 8);
    int c = 0;
#pragma unroll 1
    for (; c + 32 <= 72; c += 16) {
        cp(ra, c);     ld(ra, c + 16);
        cp(rb, c + 8); ld(rb, c + 24);
    }
    cp(ra, 48); ld(ra, 64);
    cp(rb, 56);
    cp(ra, 64);

    float r = bout[0];
#pragma unroll
    for (int o = 0; o < 36; ++o) r += ow[o] * fmaxf(acc[o >> 1][o & 1] + sh6l[o], 0.f);
    outp[(size_t)nb * 4096 + n] = r;
}

extern "C" void kernel_launch(void* const* d_in, const int* in_sizes, int n_in,
                              void* d_out, int out_size, void* d_ws, size_t ws_size,
                              hipStream_t stream) {
    const int B = 2, Q = 16, N0 = 4096, N1 = 1024, N2 = 256;
    const int I1 = 144;
    const int NB = B * Q;  // 32

    const float* x     = (const float*)d_in[0];
    const float* mask  = (const float*)d_in[1];
    const float* sa0f  = (const float*)d_in[2];
    const float* sa1f  = (const float*)d_in[3];
    const float* xyz0  = (const float*)d_in[4];
    const float* xyz1  = (const float*)d_in[5];
    const float* xyz2  = (const float*)d_in[6];

    float* ws = (float*)d_ws;
    size_t off = 0;
    auto alloc = [&](size_t n) { size_t p = off; off += (n + 15) & ~(size_t)15; return p; };

    size_t wgt1  = alloc((size_t)B * N1 * 3);
    size_t wgt2  = alloc((size_t)B * N0 * 3);
    size_t idx1  = alloc((size_t)B * N1 * 3);
    size_t idx2  = alloc((size_t)B * N0 * 3);
    size_t slotA = alloc((size_t)NB * 296 * N2);  // h1 / g3t / h4
    size_t slotB = alloc((size_t)NB * I1 * N1);   // h2 / h3 / g5t
    size_t base1 = alloc((size_t)B * 296 * N2);
    size_t base3 = alloc((size_t)B * I1 * N1);
    size_t wt1 = alloc(296 * 296), sb1 = alloc(296);
    size_t wt2 = alloc(296 * 144), sb2 = alloc(144);
    size_t wt3 = alloc(288 * 144), sb3 = alloc(144);
    size_t wt4 = alloc(144 * 72),  sb4 = alloc(72);
    size_t wt5 = alloc(144 * 72),  sb5 = alloc(72);
    size_t wt6 = alloc(72 * 36),   sb6 = alloc(36);
    size_t w3c = alloc(128 * 144), sh3 = alloc(144);
    size_t w5c = alloc(3 * 72),    sh5 = alloc(72);
    (void)ws_size; (void)in_sizes; (void)n_in;

    auto din = [&](int i) { return (const float*)d_in[i]; };

    HeadArgs ha;
    ha.l[0] = { din(7),  din(8),  din(9),  ws + wt1, ws + sb1, 296, 296 };
    ha.l[1] = { din(10), din(11), din(12), ws + wt2, ws + sb2, 144, 296 };
    ha.l[2] = { din(17), din(18), din(19), ws + wt3, ws + sb3, 144, 288 };
    ha.l[3] = { din(20), din(21), din(22), ws + wt4, ws + sb4, 72, 144 };
    ha.l[4] = { din(23), din(24), din(25), ws + wt5, ws + sb5, 72, 144 };
    ha.l[5] = { din(26), din(27), din(28), ws + wt6, ws + sb6, 36, 72 };
    ha.a2w = din(15); ha.a2b = din(16); ha.w3 = din(17); ha.b3 = din(18); ha.bn3 = din(19);
    ha.w3c = ws + w3c; ha.sh3 = ws + sh3;
    ha.a1w = din(13); ha.a1b = din(14); ha.w5 = din(23); ha.b5 = din(24); ha.bn5 = din(25);
    ha.w5c = ws + w5c; ha.sh5 = ws + sh5;
    ha.xyz0 = xyz0; ha.xyz1 = xyz1; ha.xyz2 = xyz2;
    ha.idx1 = (int*)(ws + idx1); ha.wgt1 = ws + wgt1;
    ha.idx2 = (int*)(ws + idx2); ha.wgt2 = ws + wgt2;
    head_kernel<<<dim3(171 + 64 + 256), 256, 0, stream>>>(ha);

    // per-b bases (base1 | base3), 4-wave K-split
    bases_kernel<<<dim3(436), 256, 0, stream>>>(
        x, sa1f, ws + wt1, ws + sb1, ws + w3c, ws + sh3, ws + base1, ws + base3);

    // h1 = ReLU(W1[:,288:] @ mask + base1) -> slotA   [2368 1-wave blocks]
    conv_swz<8, 296, 4, true, 2><<<dim3(2368), 64, 0, stream>>>(
        mask, 1, ws + wt1 + 288 * 296, ws + sb1, ws + base1, Q, ws + slotA, N2, 1, 74);

    // h2 -> slotB   [1152 blocks x 4 waves, K-split 80+72+72+72]
    conv_ks4<80, 72, 72, 72, 144, true, 1, false><<<dim3(1152), 256, 0, stream>>>(
        ws + slotA, 1, ws + wt2, ws + sb2, nullptr, 1, ws + slotB, N2, 1, 36);

    // g3t = (W3a @ h2)^T  (NB, 256, 144) -> slotA   [1152 blocks, K 36x4]
    conv_ks4<36, 36, 36, 36, 144, false, 0, true><<<dim3(1152), 256, 0, stream>>>(
        ws + slotB, 1, ws + wt3, ws + sb3, nullptr, 1, ws + slotA, N2, 1, 36);

    // h3 = ReLU(gather(g3t) + base3) -> slotB   [1024 blocks, c-split x2]
    gather_t1_kernel<<<dim3(1024), 64, 0, stream>>>(
        ws + slotA, (const int*)(ws + idx1), ws + wgt1, ws + base3, ws + slotB);

    // h4 = ReLU(W4 @ h3 + shb4) -> slotA   [2304 blocks, K 36x4]
    conv_ks4<36, 36, 36, 36, 72, true, 1, false><<<dim3(2304), 256, 0, stream>>>(
        ws + slotB, 1, ws + wt4, ws + sb4, nullptr, 1, ws + slotA, N1, 4, 18);

    // g5t = (W5a @ h4)^T  (NB, 1024, 72) -> slotB   [2304 blocks, K 20+20+16+16]
    conv_ks4<20, 20, 16, 16, 72, false, 0, true><<<dim3(2304), 256, 0, stream>>>(
        ws + slotA, 1, ws + wt5, ws + sb5, nullptr, 1, ws + slotB, N1, 4, 18);

    // fused gather2 + base5 + h6 + out -> d_out   [2048 1-wave blocks]
    h6out_kernel<<<dim3(2048), 64, 0, stream>>>(
        ws + slotB, (const int*)(ws + idx2), ws + wgt2, sa0f,
        ws + w5c, ws + sh5, ws + wt6, ws + sb6, din(29), din(30), (float*)d_out);
}